// Round 2
// baseline (166.245 us; speedup 1.0000x reference)
//
#include <hip/hip_runtime.h>
#include <type_traits>

typedef unsigned short u16;
typedef __attribute__((ext_vector_type(8))) short short8;
typedef __attribute__((ext_vector_type(4))) float floatx4;

__device__ __forceinline__ u16 f2u(float f) {
  unsigned int x = __float_as_uint(f);
  x += 0x7fff + ((x >> 16) & 1);  // RNE to bf16
  return (u16)(x >> 16);
}

__device__ __forceinline__ void async16(const void* g, void* l) {
  __builtin_amdgcn_global_load_lds(
      (const __attribute__((address_space(1))) unsigned int*)g,
      (__attribute__((address_space(3))) unsigned int*)l, 16, 0, 0);
}

// d[j] = sum_i 4*c_i/(a_i-b_i)^2 * relu((a_i - lam_j)(lam_j - b_i))
__global__ void compute_d_kernel(const float* __restrict__ lam,
                                 const float* __restrict__ a,
                                 const float* __restrict__ b,
                                 const float* __restrict__ c,
                                 float* __restrict__ d, int n) {
  int j = blockIdx.x * blockDim.x + threadIdx.x;
  if (j >= n) return;
  float lv = lam[(size_t)j * n + j];
  float acc = 0.f;
#pragma unroll
  for (int i = 0; i < 4; ++i) {
    float ai = a[i], bi = b[i], ci = c[i];
    float rep = (ai - lv) * (lv - bi);
    rep = rep > 0.f ? rep : 0.f;
    acc += ci * 4.f / ((ai - bi) * (ai - bi)) * rep;
  }
  d[j] = acc;
}

// in[R][C] fp32 -> outT[C][R] bf16 (transpose+cast); optionally outC[R][C]
// bf16 straight cast. 64x64 tiles, 256 threads.
__global__ __launch_bounds__(256) void transpose_cast_kernel(
    const float* __restrict__ in, u16* __restrict__ outT,
    u16* __restrict__ outC, int R, int C) {
  __shared__ __attribute__((aligned(16))) float tile[64][65];
  int c0 = blockIdx.x * 64, r0 = blockIdx.y * 64;
  int t = threadIdx.x;
#pragma unroll
  for (int p = 0; p < 4; ++p) {
    int e = p * 256 + t;
    int row = e >> 4, col = (e & 15) * 4;
    float4 v = *(const float4*)(in + (size_t)(r0 + row) * C + c0 + col);
    tile[row][col] = v.x;
    tile[row][col + 1] = v.y;
    tile[row][col + 2] = v.z;
    tile[row][col + 3] = v.w;
    if (outC) {
      u16* o = outC + (size_t)(r0 + row) * C + c0 + col;
      o[0] = f2u(v.x); o[1] = f2u(v.y); o[2] = f2u(v.z); o[3] = f2u(v.w);
    }
  }
  __syncthreads();
#pragma unroll
  for (int p = 0; p < 2; ++p) {
    int e = p * 256 + t;
    int orow = e >> 3, oc = (e & 7) * 8;  // outT row c0+orow, cols r0+oc..+7
    union { uint4 v; u16 s[8]; } tmp;
#pragma unroll
    for (int i = 0; i < 8; ++i) tmp.s[i] = f2u(tile[oc + i][orow]);
    *(uint4*)(outT + (size_t)(c0 + orow) * R + r0 + oc) = tmp.v;
  }
}

// C[m][col] = sum_k A[m][k]*B[col][k]  (both operands bf16, k-contiguous)
// SCALE_D: *= dvec[col].  RESIDUAL: += alpha_p[0] * resid[m][col] (fp32).
// CT = u16 (bf16 store) or float.
template <bool SCALE_D, bool RESIDUAL, typename CT>
__global__ __launch_bounds__(256) void gemm_tn(
    const u16* __restrict__ A, const u16* __restrict__ B, CT* __restrict__ C,
    int M, int NN, int K, const float* __restrict__ dvec,
    const float* __restrict__ resid, const float* __restrict__ alpha_p) {
  // BM=128, BN=64, BK=32; 4 waves 2x2; each wave 64x32 = 4x2 MFMA tiles
  __shared__ __attribute__((aligned(16))) u16 lA[128 * 32];
  __shared__ __attribute__((aligned(16))) u16 lB[64 * 32];
  const int m0 = blockIdx.x * 128;
  const int n0 = blockIdx.y * 64;
  const int t = threadIdx.x;
  const int wave = t >> 6, lane = t & 63;
  const int wm = wave >> 1, wn = wave & 1;
  const int q = lane >> 4, l15 = lane & 15;

  const u16* gA = A + (size_t)(m0 + (t >> 2)) * K + (t & 3) * 8;
  const u16* gB = B + (size_t)(n0 + (t >> 2)) * K + (t & 3) * 8;
  char* lAw0 = (char*)lA + wave * 1024;
  char* lAw1 = (char*)lA + 4096 + wave * 1024;
  char* lBw = (char*)lB + wave * 1024;

  floatx4 acc[4][2];
#pragma unroll
  for (int i = 0; i < 4; ++i)
#pragma unroll
    for (int j = 0; j < 2; ++j) acc[i][j] = (floatx4){0.f, 0.f, 0.f, 0.f};

  for (int k0 = 0; k0 < K; k0 += 32) {
    __syncthreads();  // prev iter's ds_reads done -> LDS reusable
    async16(gA + k0, lAw0);
    async16(gA + (size_t)64 * K + k0, lAw1);
    async16(gB + k0, lBw);
    __syncthreads();  // vmcnt(0) drain: tiles resident
    short8 af[4], bfr[2];
#pragma unroll
    for (int mt = 0; mt < 4; ++mt)
      af[mt] = *(const short8*)&lA[(wm * 64 + mt * 16 + l15) * 32 + q * 8];
#pragma unroll
    for (int nt = 0; nt < 2; ++nt)
      bfr[nt] = *(const short8*)&lB[(wn * 32 + nt * 16 + l15) * 32 + q * 8];
#pragma unroll
    for (int mt = 0; mt < 4; ++mt)
#pragma unroll
      for (int nt = 0; nt < 2; ++nt)
        acc[mt][nt] = __builtin_amdgcn_mfma_f32_16x16x32_bf16(
            af[mt], bfr[nt], acc[mt][nt], 0, 0, 0);
  }

  // C/D layout: col=lane&15, row=(lane>>4)*4+reg  [m89/m91]
  float alpha = 0.f;
  if (RESIDUAL) alpha = alpha_p[0];
#pragma unroll
  for (int nt = 0; nt < 2; ++nt) {
    int col = n0 + wn * 32 + nt * 16 + l15;
    float ds = 1.f;
    if (SCALE_D) ds = dvec[col];
#pragma unroll
    for (int mt = 0; mt < 4; ++mt) {
      int rbase = m0 + wm * 64 + mt * 16 + q * 4;
#pragma unroll
      for (int r = 0; r < 4; ++r) {
        float v = acc[mt][nt][r];
        if (SCALE_D) v *= ds;
        size_t idx = (size_t)(rbase + r) * NN + col;
        if (RESIDUAL) v += alpha * resid[idx];
        if constexpr (std::is_same<CT, u16>::value)
          C[idx] = f2u(v);
        else
          C[idx] = v;
      }
    }
  }
}

extern "C" void kernel_launch(void* const* d_in, const int* in_sizes, int n_in,
                              void* d_out, int out_size, void* d_ws,
                              size_t ws_size, hipStream_t stream) {
  const int N = 2048, F = 256;
  const float* x = (const float*)d_in[0];     // [N][F] fp32
  const float* lam = (const float*)d_in[1];   // [N][N] fp32 (diag)
  const float* U = (const float*)d_in[2];     // [N][N] fp32
  const float* a = (const float*)d_in[3];
  const float* b = (const float*)d_in[4];
  const float* c = (const float*)d_in[5];
  const float* alpha = (const float*)d_in[6];
  // d_in[7] = edge_index: unused by the reference math

  char* ws = (char*)d_ws;
  float* dvec = (float*)ws;                             // 8 KB
  u16* xT = (u16*)(ws + 8192);                          // [F][N] bf16, 1 MB
  u16* Ut = (u16*)(ws + 8192 + (1 << 20));              // [N][N] bf16 (U^T), 8 MB
  u16* Ubf = (u16*)(ws + 8192 + (1 << 20) + (8 << 20)); // [N][N] bf16, 8 MB
  u16* wT = (u16*)(ws + 8192 + (1 << 20) + (16 << 20)); // [F][N] bf16, 1 MB

  compute_d_kernel<<<8, 256, 0, stream>>>(lam, a, b, c, dvec, N);
  // U -> Ut (transposed bf16) + Ubf (straight bf16), one read of U
  transpose_cast_kernel<<<dim3(32, 32), 256, 0, stream>>>(U, Ut, Ubf, N, N);
  // x -> xT (transposed bf16)
  transpose_cast_kernel<<<dim3(4, 32), 256, 0, stream>>>(x, xT, nullptr, N, F);
  // GEMM1: wT[f][j] = d[j] * sum_n xT[f][n] * Ut[j][n]   (bf16 out)
  gemm_tn<true, false, u16><<<dim3(2, 32), 256, 0, stream>>>(
      xT, Ut, wT, F, N, N, dvec, nullptr, nullptr);
  // GEMM2: out[n][f] = alpha*x[n][f] + sum_j Ubf[n][j] * wT[f][j]  (fp32 out)
  gemm_tn<false, true, float><<<dim3(16, 4), 256, 0, stream>>>(
      Ubf, wT, (float*)d_out, N, F, N, nullptr, x, alpha);
}

// Round 3
// 120.456 us; speedup vs baseline: 1.3801x; 1.3801x over previous
//
#include <hip/hip_runtime.h>

typedef unsigned short u16;
typedef __attribute__((ext_vector_type(8))) short short8;
typedef __attribute__((ext_vector_type(4))) float floatx4;

__device__ __forceinline__ u16 f2u(float f) {
  unsigned int x = __float_as_uint(f);
  x += 0x7fff + ((x >> 16) & 1);  // RNE to bf16
  return (u16)(x >> 16);
}

__device__ __forceinline__ void async16(const void* g, void* l) {
  __builtin_amdgcn_global_load_lds(
      (const __attribute__((address_space(1))) unsigned int*)g,
      (__attribute__((address_space(3))) unsigned int*)l, 16, 0, 0);
}

// d[j] = sum_i 4*c_i/(a_i-b_i)^2 * relu((a_i - lam_j)(lam_j - b_i))
__global__ void compute_d_kernel(const float* __restrict__ lam,
                                 const float* __restrict__ a,
                                 const float* __restrict__ b,
                                 const float* __restrict__ c,
                                 float* __restrict__ d, int n) {
  int j = blockIdx.x * blockDim.x + threadIdx.x;
  if (j >= n) return;
  float lv = lam[(size_t)j * n + j];
  float acc = 0.f;
#pragma unroll
  for (int i = 0; i < 4; ++i) {
    float ai = a[i], bi = b[i], ci = c[i];
    float rep = (ai - lv) * (lv - bi);
    rep = rep > 0.f ? rep : 0.f;
    acc += ci * 4.f / ((ai - bi) * (ai - bi)) * rep;
  }
  d[j] = acc;
}

// in[R][C] fp32 -> outT[C][R] bf16 (transpose+cast); optionally outC[R][C]
// bf16 straight cast (vectorized 8B stores). 64x64 tiles, 256 threads.
__global__ __launch_bounds__(256) void transpose_cast_kernel(
    const float* __restrict__ in, u16* __restrict__ outT,
    u16* __restrict__ outC, int R, int C) {
  __shared__ __attribute__((aligned(16))) float tile[64][65];
  int c0 = blockIdx.x * 64, r0 = blockIdx.y * 64;
  int t = threadIdx.x;
#pragma unroll
  for (int p = 0; p < 4; ++p) {
    int e = p * 256 + t;
    int row = e >> 4, col = (e & 15) * 4;
    float4 v = *(const float4*)(in + (size_t)(r0 + row) * C + c0 + col);
    tile[row][col] = v.x;
    tile[row][col + 1] = v.y;
    tile[row][col + 2] = v.z;
    tile[row][col + 3] = v.w;
    if (outC) {
      union { uint2 u; u16 s[4]; } pk;
      pk.s[0] = f2u(v.x); pk.s[1] = f2u(v.y);
      pk.s[2] = f2u(v.z); pk.s[3] = f2u(v.w);
      *(uint2*)(outC + (size_t)(r0 + row) * C + c0 + col) = pk.u;
    }
  }
  __syncthreads();
#pragma unroll
  for (int p = 0; p < 2; ++p) {
    int e = p * 256 + t;
    int orow = e >> 3, oc = (e & 7) * 8;  // outT row c0+orow, cols r0+oc..+7
    union { uint4 v; u16 s[8]; } tmp;
#pragma unroll
    for (int i = 0; i < 8; ++i) tmp.s[i] = f2u(tile[oc + i][orow]);
    *(uint4*)(outT + (size_t)(c0 + orow) * R + r0 + oc) = tmp.v;
  }
}

// Split-K TN GEMM: P[bz][m][col] = sum_{k in slice bz} A[m][k]*B[col][k]
// A: [M][K] bf16 row-major (k contiguous). B: [NN][K] bf16 row-major.
// P: [S][M][NN] fp32 partials. BM=BN=64, BK=32, 4 waves 2x2 (32x32 each).
__global__ __launch_bounds__(256) void gemm_tn_split(
    const u16* __restrict__ A, const u16* __restrict__ B,
    float* __restrict__ P, int M, int NN, int K, int Ks) {
  __shared__ __attribute__((aligned(16))) u16 lA[64 * 32];
  __shared__ __attribute__((aligned(16))) u16 lB[64 * 32];
  const int m0 = blockIdx.x * 64;
  const int n0 = blockIdx.y * 64;
  const int kbase = blockIdx.z * Ks;
  const int t = threadIdx.x;
  const int wave = t >> 6, lane = t & 63;
  const int wm = wave >> 1, wn = wave & 1;
  const int q = lane >> 4, l15 = lane & 15;

  // staging: thread t moves 16B; row = t>>2 (64 rows x 64B), col16 = t&3
  const u16* gA = A + (size_t)(m0 + (t >> 2)) * K + (t & 3) * 8;
  const u16* gB = B + (size_t)(n0 + (t >> 2)) * K + (t & 3) * 8;
  char* lAw = (char*)lA + wave * 1024;
  char* lBw = (char*)lB + wave * 1024;

  floatx4 acc[2][2];
#pragma unroll
  for (int i = 0; i < 2; ++i)
#pragma unroll
    for (int j = 0; j < 2; ++j) acc[i][j] = (floatx4){0.f, 0.f, 0.f, 0.f};

  for (int k0 = kbase; k0 < kbase + Ks; k0 += 32) {
    __syncthreads();  // prev iter's ds_reads done -> LDS reusable
    async16(gA + k0, lAw);
    async16(gB + k0, lBw);
    __syncthreads();  // vmcnt(0) drain: tiles resident
    short8 af[2], bfr[2];
#pragma unroll
    for (int mt = 0; mt < 2; ++mt)
      af[mt] = *(const short8*)&lA[(wm * 32 + mt * 16 + l15) * 32 + q * 8];
#pragma unroll
    for (int nt = 0; nt < 2; ++nt)
      bfr[nt] = *(const short8*)&lB[(wn * 32 + nt * 16 + l15) * 32 + q * 8];
#pragma unroll
    for (int mt = 0; mt < 2; ++mt)
#pragma unroll
      for (int nt = 0; nt < 2; ++nt)
        acc[mt][nt] = __builtin_amdgcn_mfma_f32_16x16x32_bf16(
            af[mt], bfr[nt], acc[mt][nt], 0, 0, 0);
  }

  // C/D layout: col=lane&15, row=(lane>>4)*4+reg  [m89/m91]
  float* Pz = P + (size_t)blockIdx.z * M * NN;
#pragma unroll
  for (int nt = 0; nt < 2; ++nt) {
    int col = n0 + wn * 32 + nt * 16 + l15;
#pragma unroll
    for (int mt = 0; mt < 2; ++mt) {
      int rbase = m0 + wm * 32 + mt * 16 + q * 4;
#pragma unroll
      for (int r = 0; r < 4; ++r)
        Pz[(size_t)(rbase + r) * NN + col] = acc[mt][nt][r];
    }
  }
}

// zT[i] = d[i % NN] * sum_s P[s][i], cast to bf16. 4 elems/thread.
__global__ __launch_bounds__(256) void reduce_scale_bf16(
    const float* __restrict__ P, const float* __restrict__ dvec,
    u16* __restrict__ zT, int total, int NN, int S) {
  int i4 = (blockIdx.x * 256 + threadIdx.x) * 4;
  if (i4 >= total) return;
  float4 acc = *(const float4*)(P + i4);
  for (int s = 1; s < S; ++s) {
    float4 v = *(const float4*)(P + (size_t)s * total + i4);
    acc.x += v.x; acc.y += v.y; acc.z += v.z; acc.w += v.w;
  }
  float4 dv = *(const float4*)(dvec + (i4 & (NN - 1)));
  union { uint2 u; u16 s[4]; } pk;
  pk.s[0] = f2u(acc.x * dv.x); pk.s[1] = f2u(acc.y * dv.y);
  pk.s[2] = f2u(acc.z * dv.z); pk.s[3] = f2u(acc.w * dv.w);
  *(uint2*)(zT + i4) = pk.u;
}

// out[i] = alpha * x[i] + sum_s P[s][i]  (fp32)
__global__ __launch_bounds__(256) void reduce_residual(
    const float* __restrict__ P, const float* __restrict__ x,
    const float* __restrict__ alpha_p, float* __restrict__ out,
    int total, int S) {
  int i4 = (blockIdx.x * 256 + threadIdx.x) * 4;
  if (i4 >= total) return;
  float alpha = alpha_p[0];
  float4 xv = *(const float4*)(x + i4);
  float4 acc;
  acc.x = alpha * xv.x; acc.y = alpha * xv.y;
  acc.z = alpha * xv.z; acc.w = alpha * xv.w;
  for (int s = 0; s < S; ++s) {
    float4 v = *(const float4*)(P + (size_t)s * total + i4);
    acc.x += v.x; acc.y += v.y; acc.z += v.z; acc.w += v.w;
  }
  *(float4*)(out + i4) = acc;
}

extern "C" void kernel_launch(void* const* d_in, const int* in_sizes, int n_in,
                              void* d_out, int out_size, void* d_ws,
                              size_t ws_size, hipStream_t stream) {
  const int N = 2048, F = 256, S = 4;
  const float* x = (const float*)d_in[0];     // [N][F] fp32
  const float* lam = (const float*)d_in[1];   // [N][N] fp32 (diag)
  const float* U = (const float*)d_in[2];     // [N][N] fp32
  const float* a = (const float*)d_in[3];
  const float* b = (const float*)d_in[4];
  const float* c = (const float*)d_in[5];
  const float* alpha = (const float*)d_in[6];
  // d_in[7] = edge_index: unused by the reference math

  char* ws = (char*)d_ws;
  float* dvec = (float*)ws;                               // 8 KB
  u16* xT = (u16*)(ws + 8192);                            // [F][N] bf16 1 MB
  u16* Ut = (u16*)(ws + 8192 + (1 << 20));                // [N][N] bf16 8 MB
  u16* Ubf = (u16*)(ws + 8192 + (9 << 20));               // [N][N] bf16 8 MB
  u16* zT = (u16*)(ws + 8192 + (17 << 20));               // [F][N] bf16 1 MB
  float* p1 = (float*)(ws + 8192 + (18 << 20));           // S*[F][N] f32 8 MB
  float* p2 = (float*)(ws + 8192 + (26 << 20));           // S*[N][F] f32 8 MB

  compute_d_kernel<<<8, 256, 0, stream>>>(lam, a, b, c, dvec, N);
  // U -> Ut (transposed bf16) + Ubf (straight bf16), one read of U
  transpose_cast_kernel<<<dim3(32, 32), 256, 0, stream>>>(U, Ut, Ubf, N, N);
  // x -> xT (transposed bf16)
  transpose_cast_kernel<<<dim3(4, 32), 256, 0, stream>>>(x, xT, nullptr, N, F);
  // GEMM1 partials: p1[s][f][j] = sum_{n in s} xT[f][n]*Ut[j][n]
  gemm_tn_split<<<dim3(F / 64, N / 64, S), 256, 0, stream>>>(
      xT, Ut, p1, F, N, N, N / S);
  // zT[f][j] = d[j] * sum_s p1[s][f][j]  (bf16)
  reduce_scale_bf16<<<(F * N / 4 + 255) / 256, 256, 0, stream>>>(
      p1, dvec, zT, F * N, N, S);
  // GEMM2 partials: p2[s][n][f] = sum_{j in s} Ubf[n][j]*zT[f][j]
  gemm_tn_split<<<dim3(N / 64, F / 64, S), 256, 0, stream>>>(
      Ubf, zT, p2, N, F, N, N / S);
  // out[n][f] = alpha*x[n][f] + sum_s p2[s][n][f]  (fp32)
  reduce_residual<<<(N * F / 4 + 255) / 256, 256, 0, stream>>>(
      p2, x, alpha, (float*)d_out, N * F, S);
}

// Round 4
// 119.238 us; speedup vs baseline: 1.3942x; 1.0102x over previous
//
#include <hip/hip_runtime.h>
#include <type_traits>

typedef unsigned short u16;
typedef __attribute__((ext_vector_type(8))) short short8;
typedef __attribute__((ext_vector_type(4))) float floatx4;

__device__ __forceinline__ u16 f2u(float f) {
  unsigned int x = __float_as_uint(f);
  x += 0x7fff + ((x >> 16) & 1);  // RNE to bf16
  return (u16)(x >> 16);
}

__device__ __forceinline__ void async16(const void* g, void* l) {
  __builtin_amdgcn_global_load_lds(
      (const __attribute__((address_space(1))) unsigned int*)g,
      (__attribute__((address_space(3))) unsigned int*)l, 16, 0, 0);
}

// One dispatch, three jobs decoded from blockIdx.x:
//  b <  1024 : U[2048][2048] fp32 -> Ut[j][n] bf16 (transpose) + Ubf bf16
//  b <  1152 : x[2048][256]  fp32 -> xT[256][2048] bf16 (transpose)
//  b <  1160 : dvec[j] = sum_i 4*c_i/(a_i-b_i)^2 * relu((a_i-lam_j)(lam_j-b_i))
__global__ __launch_bounds__(256) void prep_kernel(
    const float* __restrict__ U, const float* __restrict__ x,
    const float* __restrict__ lam, const float* __restrict__ a,
    const float* __restrict__ b, const float* __restrict__ c,
    u16* __restrict__ Ut, u16* __restrict__ Ubf, u16* __restrict__ xT,
    float* __restrict__ dvec, int N, int F) {
  __shared__ __attribute__((aligned(16))) float tile[64][65];
  int bb = blockIdx.x;
  int t = threadIdx.x;

  if (bb >= 1152) {  // d job: 8 blocks x 256 threads = 2048
    int j = (bb - 1152) * 256 + t;
    float lv = lam[(size_t)j * N + j];
    float acc = 0.f;
#pragma unroll
    for (int i = 0; i < 4; ++i) {
      float ai = a[i], bi = b[i], ci = c[i];
      float rep = (ai - lv) * (lv - bi);
      rep = rep > 0.f ? rep : 0.f;
      acc += ci * 4.f / ((ai - bi) * (ai - bi)) * rep;
    }
    dvec[j] = acc;
    return;
  }

  const float* in;
  u16 *outT, *outC;
  int R, C, c0, r0;
  if (bb < 1024) {  // U job
    in = U; outT = Ut; outC = Ubf; R = N; C = N;
    c0 = (bb & 31) * 64; r0 = (bb >> 5) * 64;
  } else {  // x job
    int b2 = bb - 1024;
    in = x; outT = xT; outC = nullptr; R = N; C = F;
    c0 = (b2 & 3) * 64; r0 = (b2 >> 2) * 64;
  }

#pragma unroll
  for (int p = 0; p < 4; ++p) {
    int e = p * 256 + t;
    int row = e >> 4, col = (e & 15) * 4;
    float4 v = *(const float4*)(in + (size_t)(r0 + row) * C + c0 + col);
    tile[row][col] = v.x;
    tile[row][col + 1] = v.y;
    tile[row][col + 2] = v.z;
    tile[row][col + 3] = v.w;
    if (outC) {
      union { uint2 u; u16 s[4]; } pk;
      pk.s[0] = f2u(v.x); pk.s[1] = f2u(v.y);
      pk.s[2] = f2u(v.z); pk.s[3] = f2u(v.w);
      *(uint2*)(outC + (size_t)(r0 + row) * C + c0 + col) = pk.u;
    }
  }
  __syncthreads();
#pragma unroll
  for (int p = 0; p < 2; ++p) {
    int e = p * 256 + t;
    int orow = e >> 3, oc = (e & 7) * 8;
    union { uint4 v; u16 s[8]; } tmp;
#pragma unroll
    for (int i = 0; i < 8; ++i) tmp.s[i] = f2u(tile[oc + i][orow]);
    *(uint4*)(outT + (size_t)(c0 + orow) * R + r0 + oc) = tmp.v;
  }
}

// Direct TN GEMM, no split-K: C[m][col] = sum_k A[m][k]*B[col][k]
// A: [M][K] bf16 (k contig). B: [NN][K] bf16 (k contig).
// BM=64, BN=32; 4 waves 2x2 (each 32x16 = 2x1 MFMA tiles).
// K-loop: macro BK=128 (4 sub-tiles of 32), double-buffered LDS, one
// __syncthreads per macro-iter; prefetch issued after the barrier so its
// latency hides behind the current tile's ds_read+MFMA.
// SCALE_D: *= dvec[col].  RESIDUAL: += alpha_p[0]*resid[idx] (fp32).
template <bool SCALE_D, bool RESIDUAL, typename CT>
__global__ __launch_bounds__(256) void gemm_tn(
    const u16* __restrict__ A, const u16* __restrict__ B, CT* __restrict__ C,
    int M, int NN, int K, const float* __restrict__ dvec,
    const float* __restrict__ resid, const float* __restrict__ alpha_p) {
  // lA: 2 bufs x 4 subtiles x (64x32 u16, 4 KB) = 32 KB
  // lB: 2 bufs x 4 subtiles x (32x32 u16, 2 KB) = 16 KB
  __shared__ __attribute__((aligned(16))) u16 lA[2 * 4 * 64 * 32];
  __shared__ __attribute__((aligned(16))) u16 lB[2 * 4 * 32 * 32];
  const int m0 = blockIdx.x * 64;
  const int n0 = blockIdx.y * 32;
  const int t = threadIdx.x;
  const int wave = t >> 6;
  const int lane = t & 63;
  const int wm = wave >> 1, wn = wave & 1;
  const int q = lane >> 4, l15 = lane & 15;

  // staging ptrs: A sub-tile = 64 rows x 64 B (256 x 16B chunks, 1/thread)
  //               B sub-tile = 32 rows x 64 B (128 chunks, threads 0..127)
  const u16* gA = A + (size_t)(m0 + (t >> 2)) * K + (t & 3) * 8;
  const u16* gB = B + (size_t)(n0 + ((t & 127) >> 2)) * K + (t & 3) * 8;
  char* lAc = (char*)lA;
  char* lBc = (char*)lB;

  const int NM = K >> 7;  // macro-iters

  auto issue = [&](int i, int buf) {
#pragma unroll
    for (int st = 0; st < 4; ++st)
      async16(gA + i * 128 + st * 32, lAc + buf * 16384 + st * 4096 + t * 16);
    if (t < 128) {
#pragma unroll
      for (int st = 0; st < 4; ++st)
        async16(gB + i * 128 + st * 32, lBc + buf * 8192 + st * 2048 + t * 16);
    }
  };

  floatx4 acc[2];
  acc[0] = (floatx4){0.f, 0.f, 0.f, 0.f};
  acc[1] = (floatx4){0.f, 0.f, 0.f, 0.f};

  issue(0, 0);
  for (int i = 0; i < NM; ++i) {
    const int buf = i & 1;
    __syncthreads();  // drains buf's loads; all waves done reading buf^1
    if (i + 1 < NM) issue(i + 1, buf ^ 1);
    const u16* lAb = lA + buf * 8192;  // u16 units
    const u16* lBb = lB + buf * 4096;
#pragma unroll
    for (int st = 0; st < 4; ++st) {
      short8 a0 = *(const short8*)&lAb[st * 2048 + (wm * 32 + l15) * 32 + q * 8];
      short8 a1 = *(const short8*)&lAb[st * 2048 + (wm * 32 + 16 + l15) * 32 + q * 8];
      short8 bf = *(const short8*)&lBb[st * 1024 + (wn * 16 + l15) * 32 + q * 8];
      acc[0] = __builtin_amdgcn_mfma_f32_16x16x32_bf16(a0, bf, acc[0], 0, 0, 0);
      acc[1] = __builtin_amdgcn_mfma_f32_16x16x32_bf16(a1, bf, acc[1], 0, 0, 0);
    }
  }

  // C/D layout: col=lane&15, row=(lane>>4)*4+reg  [m89/m91]
  float alpha = 0.f;
  if (RESIDUAL) alpha = alpha_p[0];
  const int col = n0 + wn * 16 + l15;
  float ds = 1.f;
  if (SCALE_D) ds = dvec[col];
#pragma unroll
  for (int mt = 0; mt < 2; ++mt) {
    int rbase = m0 + wm * 32 + mt * 16 + q * 4;
#pragma unroll
    for (int r = 0; r < 4; ++r) {
      float v = acc[mt][r];
      if (SCALE_D) v *= ds;
      size_t idx = (size_t)(rbase + r) * NN + col;
      if (RESIDUAL) v += alpha * resid[idx];
      if constexpr (std::is_same<CT, u16>::value)
        C[idx] = f2u(v);
      else
        C[idx] = v;
    }
  }
}

extern "C" void kernel_launch(void* const* d_in, const int* in_sizes, int n_in,
                              void* d_out, int out_size, void* d_ws,
                              size_t ws_size, hipStream_t stream) {
  const int N = 2048, F = 256;
  const float* x = (const float*)d_in[0];     // [N][F] fp32
  const float* lam = (const float*)d_in[1];   // [N][N] fp32 (diag)
  const float* U = (const float*)d_in[2];     // [N][N] fp32
  const float* a = (const float*)d_in[3];
  const float* b = (const float*)d_in[4];
  const float* c = (const float*)d_in[5];
  const float* alpha = (const float*)d_in[6];
  // d_in[7] = edge_index: unused by the reference math

  char* ws = (char*)d_ws;
  float* dvec = (float*)ws;                    // 8 KB
  u16* xT = (u16*)(ws + 8192);                 // [F][N] bf16 1 MB
  u16* Ut = (u16*)(ws + 8192 + (1 << 20));     // [N][N] bf16 (U^T) 8 MB
  u16* Ubf = (u16*)(ws + 8192 + (9 << 20));    // [N][N] bf16 8 MB
  u16* zT = (u16*)(ws + 8192 + (17 << 20));    // [F][N] bf16 1 MB

  // prep: Ut + Ubf + xT + dvec in one dispatch
  prep_kernel<<<1160, 256, 0, stream>>>(U, x, lam, a, b, c, Ut, Ubf, xT,
                                        dvec, N, F);
  // GEMM1: zT[f][j] = d[j] * sum_n xT[f][n]*Ut[j][n]   (bf16 out)
  gemm_tn<true, false, u16><<<dim3(F / 64, N / 32), 256, 0, stream>>>(
      xT, Ut, zT, F, N, N, dvec, nullptr, nullptr);
  // GEMM2: out[n][f] = alpha*x[n][f] + sum_j Ubf[n][j]*zT[f][j]  (fp32 out)
  gemm_tn<false, true, float><<<dim3(N / 64, F / 32), 256, 0, stream>>>(
      Ubf, zT, (float*)d_out, N, F, N, nullptr, x, alpha);
}

// Round 5
// 114.163 us; speedup vs baseline: 1.4562x; 1.0445x over previous
//
#include <hip/hip_runtime.h>
#include <type_traits>

typedef unsigned short u16;
typedef __attribute__((ext_vector_type(8))) short short8;
typedef __attribute__((ext_vector_type(4))) float floatx4;

__device__ __forceinline__ u16 f2u(float f) {
  unsigned int x = __float_as_uint(f);
  x += 0x7fff + ((x >> 16) & 1);  // RNE to bf16
  return (u16)(x >> 16);
}

__device__ __forceinline__ void async16(const void* g, void* l) {
  __builtin_amdgcn_global_load_lds(
      (const __attribute__((address_space(1))) unsigned int*)g,
      (__attribute__((address_space(3))) unsigned int*)l, 16, 0, 0);
}

// Transpose+cast, one dispatch, two jobs decoded from blockIdx.x:
//  b < 1024 : U[2048][2048] fp32 -> Ut (transposed bf16) + Ubf (straight bf16)
//  b < 1152 : x[2048][256]  fp32 -> xT[256][2048] bf16
__global__ __launch_bounds__(256) void prep_kernel(
    const float* __restrict__ U, const float* __restrict__ x,
    u16* __restrict__ Ut, u16* __restrict__ Ubf, u16* __restrict__ xT,
    int N, int F) {
  __shared__ __attribute__((aligned(16))) float tile[64][65];
  int bb = blockIdx.x;
  int t = threadIdx.x;

  const float* in;
  u16 *outT, *outC;
  int R, C, c0, r0;
  if (bb < 1024) {  // U job
    in = U; outT = Ut; outC = Ubf; R = N; C = N;
    c0 = (bb & 31) * 64; r0 = (bb >> 5) * 64;
  } else {  // x job
    int b2 = bb - 1024;
    in = x; outT = xT; outC = nullptr; R = N; C = F;
    c0 = (b2 & 3) * 64; r0 = (b2 >> 2) * 64;
  }

#pragma unroll
  for (int p = 0; p < 4; ++p) {
    int e = p * 256 + t;
    int row = e >> 4, col = (e & 15) * 4;
    float4 v = *(const float4*)(in + (size_t)(r0 + row) * C + c0 + col);
    tile[row][col] = v.x;
    tile[row][col + 1] = v.y;
    tile[row][col + 2] = v.z;
    tile[row][col + 3] = v.w;
    if (outC) {
      union { uint2 u; u16 s[4]; } pk;
      pk.s[0] = f2u(v.x); pk.s[1] = f2u(v.y);
      pk.s[2] = f2u(v.z); pk.s[3] = f2u(v.w);
      *(uint2*)(outC + (size_t)(r0 + row) * C + c0 + col) = pk.u;
    }
  }
  __syncthreads();
#pragma unroll
  for (int p = 0; p < 2; ++p) {
    int e = p * 256 + t;
    int orow = e >> 3, oc = (e & 7) * 8;
    union { uint4 v; u16 s[8]; } tmp;
#pragma unroll
    for (int i = 0; i < 8; ++i) tmp.s[i] = f2u(tile[oc + i][orow]);
    *(uint4*)(outT + (size_t)(c0 + orow) * R + r0 + oc) = tmp.v;
  }
}

// Direct TN GEMM: C[m][col] = sum_k A[m][k]*B[col][k]
// A: [M][K] bf16 (k contig). B: [NN][K] bf16 (k contig).
// BM=BN=32; 4 waves 2x2, each one 16x16 MFMA accumulator.
// Macro BK=128 (4 sub-tiles of 32), double-buffered LDS, one __syncthreads
// per macro-iter; prefetch issued right after the barrier so its latency
// hides behind the current tile's ds_read+MFMA (and the co-resident block:
// grid=512 -> 2 blocks/CU, LDS=32KB/block).
// SCALE_D: *= d(col) computed inline from lam/pa/pb/pc.
// RESIDUAL: += alpha_p[0]*resid[idx] (fp32).
template <bool SCALE_D, bool RESIDUAL, typename CT>
__global__ __launch_bounds__(256) void gemm32(
    const u16* __restrict__ A, const u16* __restrict__ B, CT* __restrict__ C,
    int M, int NN, int K, const float* __restrict__ lam,
    const float* __restrict__ pa, const float* __restrict__ pb,
    const float* __restrict__ pc, const float* __restrict__ resid,
    const float* __restrict__ alpha_p) {
  // per buf: A 4 subtiles x (32x32 u16, 2KB) = 8KB; B same. 2 bufs = 32KB.
  __shared__ __attribute__((aligned(16))) u16 lA[2 * 4 * 32 * 32];
  __shared__ __attribute__((aligned(16))) u16 lB[2 * 4 * 32 * 32];
  const int m0 = blockIdx.x * 32;
  const int n0 = blockIdx.y * 32;
  const int t = threadIdx.x;
  const int wave = t >> 6, lane = t & 63;
  const int wm = wave >> 1, wn = wave & 1;
  const int q = lane >> 4, l15 = lane & 15;

  // Staging: macro-slab per operand = 4 subtiles x 32 rows x 64B = 8KB
  // = 512 x 16B chunks. Thread t moves chunks t (subtile st0) and t+256
  // (subtile st0+2); LDS dest = base + t*16 (wave-uniform + lane*16).
  const int within = t & 127, st0 = t >> 7;  // st0 in {0,1}
  const u16* gA = A + (size_t)(m0 + (within >> 2)) * K + (within & 3) * 8;
  const u16* gB = B + (size_t)(n0 + (within >> 2)) * K + (within & 3) * 8;
  char* lAc = (char*)lA;
  char* lBc = (char*)lB;

  const int NM = K >> 7;  // macro-iters (K/128)

  auto issue = [&](int i, int buf) {
    int k0 = i * 128;
    async16(gA + k0 + st0 * 32, lAc + buf * 8192 + t * 16);
    async16(gA + k0 + (st0 + 2) * 32, lAc + buf * 8192 + 4096 + t * 16);
    async16(gB + k0 + st0 * 32, lBc + buf * 8192 + t * 16);
    async16(gB + k0 + (st0 + 2) * 32, lBc + buf * 8192 + 4096 + t * 16);
  };

  floatx4 acc = (floatx4){0.f, 0.f, 0.f, 0.f};

  issue(0, 0);
  for (int i = 0; i < NM; ++i) {
    const int buf = i & 1;
    __syncthreads();  // drains buf's prefetch; all waves done with buf^1
    if (i + 1 < NM) issue(i + 1, buf ^ 1);
    const u16* lAb = lA + buf * 4096;  // u16 units
    const u16* lBb = lB + buf * 4096;
#pragma unroll
    for (int st = 0; st < 4; ++st) {
      short8 af = *(const short8*)&lAb[st * 1024 + (wm * 16 + l15) * 32 + q * 8];
      short8 bf = *(const short8*)&lBb[st * 1024 + (wn * 16 + l15) * 32 + q * 8];
      acc = __builtin_amdgcn_mfma_f32_16x16x32_bf16(af, bf, acc, 0, 0, 0);
    }
  }

  // C/D layout: col=lane&15, row=(lane>>4)*4+reg  [m89/m91]
  const int col = n0 + wn * 16 + l15;
  float ds = 1.f;
  if (SCALE_D) {
    // d(col) = sum_i 4*c_i/(a_i-b_i)^2 * relu((a_i-lv)(lv-b_i))
    float lv = lam[(size_t)col * NN + col];
    float dacc = 0.f;
#pragma unroll
    for (int i = 0; i < 4; ++i) {
      float ai = pa[i], bi = pb[i], ci = pc[i];
      float rep = (ai - lv) * (lv - bi);
      rep = rep > 0.f ? rep : 0.f;
      dacc += ci * 4.f / ((ai - bi) * (ai - bi)) * rep;
    }
    ds = dacc;
  }
  float alpha = 0.f;
  if (RESIDUAL) alpha = alpha_p[0];
  const int rbase = m0 + wm * 16 + q * 4;
#pragma unroll
  for (int r = 0; r < 4; ++r) {
    float v = acc[r];
    if (SCALE_D) v *= ds;
    size_t idx = (size_t)(rbase + r) * NN + col;
    if (RESIDUAL) v += alpha * resid[idx];
    if constexpr (std::is_same<CT, u16>::value)
      C[idx] = f2u(v);
    else
      C[idx] = v;
  }
}

extern "C" void kernel_launch(void* const* d_in, const int* in_sizes, int n_in,
                              void* d_out, int out_size, void* d_ws,
                              size_t ws_size, hipStream_t stream) {
  const int N = 2048, F = 256;
  const float* x = (const float*)d_in[0];     // [N][F] fp32
  const float* lam = (const float*)d_in[1];   // [N][N] fp32 (diag)
  const float* U = (const float*)d_in[2];     // [N][N] fp32
  const float* a = (const float*)d_in[3];
  const float* b = (const float*)d_in[4];
  const float* c = (const float*)d_in[5];
  const float* alpha = (const float*)d_in[6];
  // d_in[7] = edge_index: unused by the reference math

  char* ws = (char*)d_ws;
  u16* xT = (u16*)ws;                          // [F][N] bf16 1 MB
  u16* Ut = (u16*)(ws + (1 << 20));            // [N][N] bf16 (U^T) 8 MB
  u16* Ubf = (u16*)(ws + (9 << 20));           // [N][N] bf16 8 MB
  u16* zT = (u16*)(ws + (17 << 20));           // [F][N] bf16 1 MB

  // prep: Ut + Ubf + xT in one dispatch
  prep_kernel<<<1152, 256, 0, stream>>>(U, x, Ut, Ubf, xT, N, F);
  // GEMM1: zT[f][j] = d[j] * sum_n xT[f][n]*Ut[j][n]   (bf16 out)
  gemm32<true, false, u16><<<dim3(F / 32, N / 32), 256, 0, stream>>>(
      xT, Ut, zT, F, N, N, lam, a, b, c, nullptr, nullptr);
  // GEMM2: out[n][f] = alpha*x[n][f] + sum_j Ubf[n][j]*zT[f][j]  (fp32 out)
  gemm32<false, true, float><<<dim3(N / 32, F / 32), 256, 0, stream>>>(
      Ubf, zT, (float*)d_out, N, F, N, nullptr, nullptr, nullptr, nullptr,
      x, alpha);
}